// Round 4
// baseline (952.973 us; speedup 1.0000x reference)
//
#include <hip/hip_runtime.h>
#include <hip/hip_bf16.h>
#include <math.h>

typedef __bf16 bf16;
typedef __bf16 bf16x8 __attribute__((ext_vector_type(8)));
typedef __bf16 bf16x4 __attribute__((ext_vector_type(4)));
typedef float  f32x4  __attribute__((ext_vector_type(4)));

__device__ __forceinline__ bf16x8 zero8() { bf16x8 z = {}; return z; }

// ---------------- convert fp32 input -> bf16 shadow ----------------
__global__ void convert_kernel(const float* __restrict__ src, bf16* __restrict__ dst, int n) {
    int i = blockIdx.x * blockDim.x + threadIdx.x;
    int stride = gridDim.x * blockDim.x;
    for (; i < n; i += stride) dst[i] = (bf16)src[i];
}

// ---------------- LayerNorm (fp32 math, bf16 io) ----------------
__global__ __launch_bounds__(256) void ln_kernel(
    const bf16* __restrict__ X, const bf16* __restrict__ w,
    const bf16* __restrict__ b, bf16* __restrict__ out)
{
    const int C = 1024;
    const int row = blockIdx.x;
    const int tid = threadIdx.x;
    const bf16* xr = X + (size_t)row * C;
    bf16x4 xv = *(const bf16x4*)(xr + tid * 4);
    float x0 = (float)xv[0], x1 = (float)xv[1], x2 = (float)xv[2], x3 = (float)xv[3];
    float s  = x0 + x1 + x2 + x3;
    float sq = x0*x0 + x1*x1 + x2*x2 + x3*x3;
#pragma unroll
    for (int off = 32; off >= 1; off >>= 1) {
        s  += __shfl_xor(s,  off, 64);
        sq += __shfl_xor(sq, off, 64);
    }
    __shared__ float red[8];
    int wave = tid >> 6;
    if ((tid & 63) == 0) { red[wave] = s; red[4 + wave] = sq; }
    __syncthreads();
    float ts = red[0] + red[1] + red[2] + red[3];
    float tq = red[4] + red[5] + red[6] + red[7];
    float mean = ts * (1.0f / C);
    float var  = tq * (1.0f / C) - mean * mean;
    float rstd = rsqrtf(var + 1e-5f);
    bf16x4 wv4 = *(const bf16x4*)(w + tid * 4);
    bf16x4 bv4 = *(const bf16x4*)(b + tid * 4);
    bf16x4 o;
    o[0] = (bf16)((x0 - mean) * rstd * (float)wv4[0] + (float)bv4[0]);
    o[1] = (bf16)((x1 - mean) * rstd * (float)wv4[1] + (float)bv4[1]);
    o[2] = (bf16)((x2 - mean) * rstd * (float)wv4[2] + (float)bv4[2]);
    o[3] = (bf16)((x3 - mean) * rstd * (float)wv4[3] + (float)bv4[3]);
    *(bf16x4*)(out + (size_t)row * C + tid * 4) = o;
}

// ---------------- GEMM: out[M,N] = act((A[M,K] @ W[N,K]^T + bias)*scale) + resid ----------------
// RT: residual element type (bf16 or float). OT: output element type (bf16 or float).
template<int ACT, class RT, class OT>
__global__ __launch_bounds__(256) void gemm_kernel(
    const bf16* __restrict__ A, const bf16* __restrict__ W,
    const bf16* __restrict__ bias, const RT* __restrict__ resid,
    OT* __restrict__ out, int M, int N, int K, float scale)
{
    const int LDP = 72;
    __shared__ bf16 As[128 * LDP];
    __shared__ bf16 Bs[128 * LDP];
    const int tid = threadIdx.x;
    const int wave = tid >> 6, lane = tid & 63;
    const int lane15 = lane & 15, quad = lane >> 4;
    const int m0 = blockIdx.x * 128;
    const int n0 = blockIdx.y * 128;
    const int wm0 = (wave >> 1) * 64;
    const int wn0 = (wave & 1) * 64;
    f32x4 acc[4][4] = {};
    const int cr = tid >> 3;
    const int cc = (tid & 7) * 8;

    for (int k0 = 0; k0 < K; k0 += 64) {
#pragma unroll
        for (int i = 0; i < 4; i++) {
            int row = cr + i * 32;
            int gm = m0 + row;
            bf16x8 v = zero8();
            if (gm < M) v = *(const bf16x8*)(A + (size_t)gm * K + k0 + cc);
            *(bf16x8*)(&As[row * LDP + cc]) = v;
        }
#pragma unroll
        for (int i = 0; i < 4; i++) {
            int row = cr + i * 32;
            bf16x8 v = *(const bf16x8*)(W + (size_t)(n0 + row) * K + k0 + cc);
            *(bf16x8*)(&Bs[row * LDP + cc]) = v;
        }
        __syncthreads();
#pragma unroll
        for (int kk = 0; kk < 2; kk++) {
            bf16x8 af[4], bfr[4];
#pragma unroll
            for (int t = 0; t < 4; t++) {
                af[t]  = *(const bf16x8*)(&As[(wm0 + t * 16 + lane15) * LDP + kk * 32 + quad * 8]);
                bfr[t] = *(const bf16x8*)(&Bs[(wn0 + t * 16 + lane15) * LDP + kk * 32 + quad * 8]);
            }
#pragma unroll
            for (int mt = 0; mt < 4; mt++)
#pragma unroll
                for (int nt = 0; nt < 4; nt++)
                    acc[mt][nt] = __builtin_amdgcn_mfma_f32_16x16x32_bf16(
                        af[mt], bfr[nt], acc[mt][nt], 0, 0, 0);
        }
        __syncthreads();
    }

#pragma unroll
    for (int mt = 0; mt < 4; mt++) {
#pragma unroll
        for (int r = 0; r < 4; r++) {
            int gm = m0 + wm0 + mt * 16 + quad * 4 + r;
            if (gm >= M) continue;
#pragma unroll
            for (int nt = 0; nt < 4; nt++) {
                int gn = n0 + wn0 + nt * 16 + lane15;
                float v = acc[mt][nt][r];
                if (bias) v += (float)bias[gn];
                v *= scale;
                if (ACT == 1) v = 0.5f * v * (1.0f + erff(v * 0.70710678118f));
                if (resid) v += (float)resid[(size_t)gm * N + gn];
                out[(size_t)gm * N + gn] = (OT)v;
            }
        }
    }
}

// ---------------- Flash attention: O[M,C] per (b,h) head slice ----------------
// Q,K pre-scaled by D^-0.25. Verified equivalent to scalar reference (r2 vs r3 bit-identical).
__global__ __launch_bounds__(256) void flash_attn_kernel(
    const bf16* __restrict__ Q, const bf16* __restrict__ Km,
    const bf16* __restrict__ V, bf16* __restrict__ O)
{
    const int S = 1500, C = 1024;
    const int LDP = 72;
    __shared__ bf16 Ks[64 * LDP];
    __shared__ bf16 Vt[64 * LDP];
    __shared__ bf16 Ps[4 * 16 * LDP];
    const int tid = threadIdx.x;
    const int wave = tid >> 6, lane = tid & 63;
    const int lane15 = lane & 15, quad = lane >> 4;
    const int b = blockIdx.y >> 4, h = blockIdx.y & 15;
    const int q0 = blockIdx.x * 64;
    const size_t headoff = (size_t)b * S * C + (size_t)h * 64;

    bf16x8 qf[2];
    qf[0] = zero8(); qf[1] = zero8();
    const int qr = q0 + wave * 16 + lane15;
    if (qr < S) {
        qf[0] = *(const bf16x8*)(Q + headoff + (size_t)qr * C + quad * 8);
        qf[1] = *(const bf16x8*)(Q + headoff + (size_t)qr * C + 32 + quad * 8);
    }

    float m_run[4], l_run[4];
    f32x4 o_acc[4] = {};
#pragma unroll
    for (int r = 0; r < 4; r++) { m_run[r] = -1e30f; l_run[r] = 0.0f; }

    for (int kt = 0; kt < 24; kt++) {
        const int j0 = kt * 64;
#pragma unroll
        for (int i = 0; i < 2; i++) {
            int c = tid + i * 256;
            int jr = c >> 3;
            int cc = (c & 7) * 8;
            int gj = j0 + jr;
            bf16x8 kv = zero8();
            if (gj < S) kv = *(const bf16x8*)(Km + headoff + (size_t)gj * C + cc);
            *(bf16x8*)(&Ks[jr * LDP + cc]) = kv;
            bf16x8 vv = zero8();
            if (gj < S) vv = *(const bf16x8*)(V + headoff + (size_t)gj * C + cc);
#pragma unroll
            for (int e = 0; e < 8; e++) Vt[(cc + e) * LDP + jr] = vv[e];
        }
        __syncthreads();

        f32x4 s[4] = {};
#pragma unroll
        for (int kk = 0; kk < 2; kk++) {
#pragma unroll
            for (int nt = 0; nt < 4; nt++) {
                bf16x8 kf = *(const bf16x8*)(&Ks[(nt * 16 + lane15) * LDP + kk * 32 + quad * 8]);
                s[nt] = __builtin_amdgcn_mfma_f32_16x16x32_bf16(qf[kk], kf, s[nt], 0, 0, 0);
            }
        }
#pragma unroll
        for (int nt = 0; nt < 4; nt++) {
            if (j0 + nt * 16 + lane15 >= S) {
#pragma unroll
                for (int r = 0; r < 4; r++) s[nt][r] = -1e30f;
            }
        }
        float mnew[4], alpha[4];
#pragma unroll
        for (int r = 0; r < 4; r++) {
            float tm = fmaxf(fmaxf(s[0][r], s[1][r]), fmaxf(s[2][r], s[3][r]));
#pragma unroll
            for (int off = 1; off < 16; off <<= 1) tm = fmaxf(tm, __shfl_xor(tm, off, 64));
            mnew[r]  = fmaxf(m_run[r], tm);
            alpha[r] = __expf(m_run[r] - mnew[r]);
            float ps = 0.0f;
#pragma unroll
            for (int nt = 0; nt < 4; nt++) {
                float p = __expf(s[nt][r] - mnew[r]);
                s[nt][r] = p;
                ps += p;
            }
#pragma unroll
            for (int off = 1; off < 16; off <<= 1) ps += __shfl_xor(ps, off, 64);
            l_run[r] = l_run[r] * alpha[r] + ps;
            m_run[r] = mnew[r];
        }
#pragma unroll
        for (int dt = 0; dt < 4; dt++)
#pragma unroll
            for (int r = 0; r < 4; r++) o_acc[dt][r] *= alpha[r];
#pragma unroll
        for (int nt = 0; nt < 4; nt++)
#pragma unroll
            for (int r = 0; r < 4; r++)
                Ps[wave * 16 * LDP + (quad * 4 + r) * LDP + nt * 16 + lane15] = (bf16)s[nt][r];
        __syncthreads();
#pragma unroll
        for (int kk = 0; kk < 2; kk++) {
            bf16x8 pf = *(const bf16x8*)(&Ps[wave * 16 * LDP + lane15 * LDP + kk * 32 + quad * 8]);
#pragma unroll
            for (int dt = 0; dt < 4; dt++) {
                bf16x8 vf = *(const bf16x8*)(&Vt[(dt * 16 + lane15) * LDP + kk * 32 + quad * 8]);
                o_acc[dt] = __builtin_amdgcn_mfma_f32_16x16x32_bf16(pf, vf, o_acc[dt], 0, 0, 0);
            }
        }
        __syncthreads();
    }

#pragma unroll
    for (int dt = 0; dt < 4; dt++) {
#pragma unroll
        for (int r = 0; r < 4; r++) {
            int row = q0 + wave * 16 + quad * 4 + r;
            if (row < S) {
                float v = o_acc[dt][r] / l_run[r];
                O[headoff + (size_t)row * C + dt * 16 + lane15] = (bf16)v;
            }
        }
    }
}

extern "C" void kernel_launch(void* const* d_in, const int* in_sizes, int n_in,
                              void* d_out, int out_size, void* d_ws, size_t ws_size,
                              hipStream_t stream) {
    float* out = (float*)d_out;                      // reference output dtype is fp32
    const float* x_f32 = (const float*)d_in[0];      // pristine fp32 residual source
    const int M = 6000, Cc = 1024, F = 4096, Aa = 256;
    const size_t MC = (size_t)M * Cc;
    bf16* ws = (bf16*)d_ws;

    bf16* h1 = ws;               // [M,C]
    bf16* q  = ws + MC;          // [M,C]
    bf16* k  = ws + 2 * MC;      // [M,C]
    bf16* v  = ws + 3 * MC;      // [M,C]
    bf16* g  = ws + 4 * MC;      // [M,F] = 4*MC
    bf16* wv = h1;
    bf16* x1 = q;
    bf16* h2 = k;
    bf16* x2 = v;
    bf16* aact = h2;

    // converted-input shadows after the pipeline region
    bf16* conv[20];
    size_t off = 8 * MC;
    for (int i = 0; i < 20; i++) {
        conv[i] = ws + off;
        off += ((size_t)in_sizes[i] + 63) & ~(size_t)63;
    }

    dim3 blk(256);
    for (int i = 0; i < 20; i++) {
        int n = in_sizes[i];
        int blocks = (n + 2047) / 2048; if (blocks < 1) blocks = 1;
        convert_kernel<<<blocks, blk, 0, stream>>>((const float*)d_in[i], conv[i], n);
    }

    const bf16 *x = conv[0], *Wq = conv[1], *bq = conv[2], *Wk = conv[3], *Wv = conv[4],
               *bv = conv[5], *Wo = conv[6], *bo = conv[7], *lnw = conv[8], *lnb = conv[9],
               *W1 = conv[10], *b1 = conv[11], *W2 = conv[12], *b2 = conv[13],
               *ln2w = conv[14], *ln2b = conv[15], *Wds = conv[16], *bds = conv[17],
               *Wus = conv[18], *bus = conv[19];

    const float scale = 0.35355339059327373f;  // 64^-0.25
    dim3 gN(47, 8);    // N=1024
    dim3 gF(47, 32);   // N=4096
    dim3 gA(47, 2);    // N=256

    ln_kernel<<<M, blk, 0, stream>>>(x, lnw, lnb, h1);
    gemm_kernel<0, bf16, bf16><<<gN, blk, 0, stream>>>(h1, Wq, bq,      (const bf16*)nullptr, q,   M, Cc, Cc, scale);
    gemm_kernel<0, bf16, bf16><<<gN, blk, 0, stream>>>(h1, Wk, nullptr, (const bf16*)nullptr, k,   M, Cc, Cc, scale);
    gemm_kernel<0, bf16, bf16><<<gN, blk, 0, stream>>>(h1, Wv, bv,      (const bf16*)nullptr, v,   M, Cc, Cc, 1.0f);
    dim3 ga(24, 64);
    flash_attn_kernel<<<ga, blk, 0, stream>>>(q, k, v, wv);
    gemm_kernel<0, float, bf16><<<gN, blk, 0, stream>>>(wv, Wo, bo, x_f32, x1, M, Cc, Cc, 1.0f);
    ln_kernel<<<M, blk, 0, stream>>>(x1, ln2w, ln2b, h2);
    gemm_kernel<1, bf16, bf16><<<gF, blk, 0, stream>>>(h2, W1, b1, (const bf16*)nullptr, g,  M, F,  Cc, 1.0f);
    gemm_kernel<0, bf16, bf16><<<gN, blk, 0, stream>>>(g,  W2, b2, x1,      x2, M, Cc, F,  1.0f);
    gemm_kernel<1, bf16, bf16><<<gA, blk, 0, stream>>>(x2, Wds, bds, (const bf16*)nullptr, aact, M, Aa, Cc, 1.0f);
    gemm_kernel<0, bf16, float><<<gN, blk, 0, stream>>>(aact, Wus, bus, x2, out, M, Cc, Aa, 1.0f);
}

// Round 5
// 871.233 us; speedup vs baseline: 1.0938x; 1.0938x over previous
//
#include <hip/hip_runtime.h>
#include <hip/hip_bf16.h>
#include <math.h>

typedef __bf16 bf16;
typedef __bf16 bf16x8 __attribute__((ext_vector_type(8)));
typedef float  f32x4  __attribute__((ext_vector_type(4)));

__device__ __forceinline__ bf16x8 zero8() { bf16x8 z = {}; return z; }

// async global->LDS, 16 B per lane; LDS dest = wave-uniform base + lane*16
__device__ __forceinline__ void load16_lds(const bf16* g, bf16* l) {
    __builtin_amdgcn_global_load_lds(
        (__attribute__((address_space(1))) void*)(g),
        (__attribute__((address_space(3))) void*)(l), 16, 0, 0);
}

// ---------------- fused weight converts (19 fp32 arrays -> bf16 shadows) ----------------
struct ConvArgs {
    const float* src[19];
    bf16* dst[19];
    int n[19];
    int bstart[20];   // cumulative block starts
};
__global__ __launch_bounds__(256) void convert_many(ConvArgs a) {
    int blk = blockIdx.x;
    int s = 0;
    while (blk >= a.bstart[s + 1]) s++;
    const float* src = a.src[s];
    bf16* dst = a.dst[s];
    int n = a.n[s];
    int i0 = (blk - a.bstart[s]) * 2048;
#pragma unroll
    for (int e = 0; e < 8; e++) {
        int i = i0 + threadIdx.x + e * 256;
        if (i < n) dst[i] = (bf16)src[i];
    }
}

// ---------------- LayerNorm (fp32 math, templated input dtype) ----------------
template<class XT>
__global__ __launch_bounds__(256) void ln_kernel(
    const XT* __restrict__ X, const bf16* __restrict__ w,
    const bf16* __restrict__ b, bf16* __restrict__ out)
{
    const int C = 1024;
    const int row = blockIdx.x;
    const int tid = threadIdx.x;
    const XT* xr = X + (size_t)row * C;
    float x0 = (float)xr[tid * 4 + 0], x1 = (float)xr[tid * 4 + 1];
    float x2 = (float)xr[tid * 4 + 2], x3 = (float)xr[tid * 4 + 3];
    float s  = x0 + x1 + x2 + x3;
    float sq = x0*x0 + x1*x1 + x2*x2 + x3*x3;
#pragma unroll
    for (int off = 32; off >= 1; off >>= 1) {
        s  += __shfl_xor(s,  off, 64);
        sq += __shfl_xor(sq, off, 64);
    }
    __shared__ float red[8];
    int wave = tid >> 6;
    if ((tid & 63) == 0) { red[wave] = s; red[4 + wave] = sq; }
    __syncthreads();
    float ts = red[0] + red[1] + red[2] + red[3];
    float tq = red[4] + red[5] + red[6] + red[7];
    float mean = ts * (1.0f / C);
    float var  = tq * (1.0f / C) - mean * mean;
    float rstd = rsqrtf(var + 1e-5f);
    float w0 = (float)w[tid*4+0], w1 = (float)w[tid*4+1], w2 = (float)w[tid*4+2], w3 = (float)w[tid*4+3];
    float b0 = (float)b[tid*4+0], b1 = (float)b[tid*4+1], b2 = (float)b[tid*4+2], b3 = (float)b[tid*4+3];
    bf16* orow = out + (size_t)row * C + tid * 4;
    orow[0] = (bf16)((x0 - mean) * rstd * w0 + b0);
    orow[1] = (bf16)((x1 - mean) * rstd * w1 + b1);
    orow[2] = (bf16)((x2 - mean) * rstd * w2 + b2);
    orow[3] = (bf16)((x3 - mean) * rstd * w3 + b3);
}

// ---------------- GEMM: out = act((A[M,K] @ W[N,K]^T + bias)*scale) + resid ----------------
// Fragment-order LDS staging via global_load_lds(16B). 128x128 tile, BK=64, 4 waves.
// TRANSV=1: write output transposed into Vt[bh=4*16][d=64][SP=1536] (for flash attention).
template<int ACT, int TRANSV, class RT, class OT>
__global__ __launch_bounds__(256) void gemm_kernel(
    const bf16* __restrict__ A, const bf16* __restrict__ W,
    const bf16* __restrict__ bias, const RT* __restrict__ resid,
    OT* __restrict__ out, int M, int N, int K, float scale)
{
    __shared__ __align__(16) bf16 As[16 * 512];   // chunk (msub*2+kk): 1 KB each
    __shared__ __align__(16) bf16 Bs[16 * 512];
    const int tid = threadIdx.x;
    const int wave = tid >> 6, lane = tid & 63;
    const int lane15 = lane & 15, quad = lane >> 4;
    const int m0 = blockIdx.x * 128;
    const int n0 = blockIdx.y * 128;
    const int wm0 = (wave >> 1) * 64;
    const int wn0 = (wave & 1) * 64;
    f32x4 acc[4][4] = {};

    // staging rows this wave owns: A/B m/n-subtiles {2w, 2w+1}
    int ra0 = m0 + (2 * wave)     * 16 + lane15; if (ra0 > M - 1) ra0 = M - 1;
    int ra1 = m0 + (2 * wave + 1) * 16 + lane15; if (ra1 > M - 1) ra1 = M - 1;
    const int rb0 = n0 + (2 * wave)     * 16 + lane15;
    const int rb1 = n0 + (2 * wave + 1) * 16 + lane15;
    const bf16* a0 = A + (size_t)ra0 * K + quad * 8;
    const bf16* a1 = A + (size_t)ra1 * K + quad * 8;
    const bf16* w0 = W + (size_t)rb0 * K + quad * 8;
    const bf16* w1 = W + (size_t)rb1 * K + quad * 8;

    for (int k0 = 0; k0 < K; k0 += 64) {
#pragma unroll
        for (int kk = 0; kk < 2; kk++) {
            load16_lds(a0 + k0 + kk * 32, &As[((2 * wave)     * 2 + kk) * 512]);
            load16_lds(a1 + k0 + kk * 32, &As[((2 * wave + 1) * 2 + kk) * 512]);
            load16_lds(w0 + k0 + kk * 32, &Bs[((2 * wave)     * 2 + kk) * 512]);
            load16_lds(w1 + k0 + kk * 32, &Bs[((2 * wave + 1) * 2 + kk) * 512]);
        }
        __syncthreads();
#pragma unroll
        for (int kk = 0; kk < 2; kk++) {
            bf16x8 af[4], bfr[4];
#pragma unroll
            for (int t = 0; t < 4; t++) {
                af[t]  = *(const bf16x8*)(&As[(((wm0 >> 4) + t) * 2 + kk) * 512 + lane * 8]);
                bfr[t] = *(const bf16x8*)(&Bs[(((wn0 >> 4) + t) * 2 + kk) * 512 + lane * 8]);
            }
#pragma unroll
            for (int mt = 0; mt < 4; mt++)
#pragma unroll
                for (int nt = 0; nt < 4; nt++)
                    acc[mt][nt] = __builtin_amdgcn_mfma_f32_16x16x32_bf16(
                        af[mt], bfr[nt], acc[mt][nt], 0, 0, 0);
        }
        __syncthreads();
    }

#pragma unroll
    for (int mt = 0; mt < 4; mt++) {
#pragma unroll
        for (int r = 0; r < 4; r++) {
            int gm = m0 + wm0 + mt * 16 + quad * 4 + r;
            if (gm >= M) continue;
#pragma unroll
            for (int nt = 0; nt < 4; nt++) {
                int gn = n0 + wn0 + nt * 16 + lane15;
                float v = acc[mt][nt][r];
                if (bias) v += (float)bias[gn];
                v *= scale;
                if (ACT == 1) v = 0.5f * v * (1.0f + erff(v * 0.70710678118f));
                if (TRANSV) {
                    int bb = gm / 1500;
                    int ss = gm - bb * 1500;
                    int hh = gn >> 6, dd = gn & 63;
                    ((bf16*)out)[(((size_t)bb * 16 + hh) * 64 + dd) * 1536 + ss] = (bf16)v;
                } else {
                    if (resid) v += (float)resid[(size_t)gm * N + gn];
                    out[(size_t)gm * N + gn] = (OT)v;
                }
            }
        }
    }
}

// ---------------- Flash attention, fragment-order staging ----------------
// Q,K pre-scaled by D^-0.25. Vt is pre-transposed [bh][d=64][SP=1536].
__global__ __launch_bounds__(256) void flash_attn_kernel(
    const bf16* __restrict__ Q, const bf16* __restrict__ Km,
    const bf16* __restrict__ Vt, bf16* __restrict__ O)
{
    const int S = 1500, C = 1024, SP = 1536;
    const int LDP = 72;
    __shared__ __align__(16) bf16 Ks[8 * 512];   // chunk (nt*2+kk)
    __shared__ __align__(16) bf16 Vs[8 * 512];   // chunk (dt*2+kk)
    __shared__ __align__(16) bf16 Ps[4 * 16 * LDP];
    const int tid = threadIdx.x;
    const int wave = tid >> 6, lane = tid & 63;
    const int lane15 = lane & 15, quad = lane >> 4;
    const int bh = blockIdx.y;
    const int q0 = blockIdx.x * 64;
    const size_t headoff = (size_t)(bh >> 4) * S * C + (size_t)(bh & 15) * 64;
    const size_t vtoff   = (size_t)bh * 64 * SP;

    bf16x8 qf[2];
    int qr = q0 + wave * 16 + lane15; if (qr > S - 1) qr = S - 1;
    qf[0] = *(const bf16x8*)(Q + headoff + (size_t)qr * C + quad * 8);
    qf[1] = *(const bf16x8*)(Q + headoff + (size_t)qr * C + 32 + quad * 8);

    const bf16* vbase = Vt + vtoff + (size_t)(wave * 16 + lane15) * SP + quad * 8;

    float m_run[4], l_run[4];
    f32x4 o_acc[4] = {};
#pragma unroll
    for (int r = 0; r < 4; r++) { m_run[r] = -1e30f; l_run[r] = 0.0f; }

    for (int kt = 0; kt < 24; kt++) {
        const int j0 = kt * 64;
        int kr = j0 + wave * 16 + lane15; if (kr > S - 1) kr = S - 1;
        const bf16* kbase = Km + headoff + (size_t)kr * C + quad * 8;
#pragma unroll
        for (int kk = 0; kk < 2; kk++) {
            load16_lds(kbase + kk * 32,      &Ks[(wave * 2 + kk) * 512]);
            load16_lds(vbase + j0 + kk * 32, &Vs[(wave * 2 + kk) * 512]);
        }
        __syncthreads();

        f32x4 s[4] = {};
#pragma unroll
        for (int kk = 0; kk < 2; kk++) {
#pragma unroll
            for (int nt = 0; nt < 4; nt++) {
                bf16x8 kf = *(const bf16x8*)(&Ks[(nt * 2 + kk) * 512 + lane * 8]);
                s[nt] = __builtin_amdgcn_mfma_f32_16x16x32_bf16(qf[kk], kf, s[nt], 0, 0, 0);
            }
        }
#pragma unroll
        for (int nt = 0; nt < 4; nt++) {
            if (j0 + nt * 16 + lane15 >= S) {
#pragma unroll
                for (int r = 0; r < 4; r++) s[nt][r] = -1e30f;
            }
        }
        float mnew[4], alpha[4];
#pragma unroll
        for (int r = 0; r < 4; r++) {
            float tm = fmaxf(fmaxf(s[0][r], s[1][r]), fmaxf(s[2][r], s[3][r]));
#pragma unroll
            for (int off = 1; off < 16; off <<= 1) tm = fmaxf(tm, __shfl_xor(tm, off, 64));
            mnew[r]  = fmaxf(m_run[r], tm);
            alpha[r] = __expf(m_run[r] - mnew[r]);
            float ps = 0.0f;
#pragma unroll
            for (int nt = 0; nt < 4; nt++) {
                float p = __expf(s[nt][r] - mnew[r]);
                s[nt][r] = p;
                ps += p;
            }
#pragma unroll
            for (int off = 1; off < 16; off <<= 1) ps += __shfl_xor(ps, off, 64);
            l_run[r] = l_run[r] * alpha[r] + ps;
            m_run[r] = mnew[r];
        }
#pragma unroll
        for (int dt = 0; dt < 4; dt++)
#pragma unroll
            for (int r = 0; r < 4; r++) o_acc[dt][r] *= alpha[r];
#pragma unroll
        for (int nt = 0; nt < 4; nt++)
#pragma unroll
            for (int r = 0; r < 4; r++)
                Ps[wave * 16 * LDP + (quad * 4 + r) * LDP + nt * 16 + lane15] = (bf16)s[nt][r];
        __syncthreads();
#pragma unroll
        for (int kk = 0; kk < 2; kk++) {
            bf16x8 pf = *(const bf16x8*)(&Ps[wave * 16 * LDP + lane15 * LDP + kk * 32 + quad * 8]);
#pragma unroll
            for (int dt = 0; dt < 4; dt++) {
                bf16x8 vf = *(const bf16x8*)(&Vs[(dt * 2 + kk) * 512 + lane * 8]);
                o_acc[dt] = __builtin_amdgcn_mfma_f32_16x16x32_bf16(pf, vf, o_acc[dt], 0, 0, 0);
            }
        }
        __syncthreads();
    }

#pragma unroll
    for (int dt = 0; dt < 4; dt++) {
#pragma unroll
        for (int r = 0; r < 4; r++) {
            int row = q0 + wave * 16 + quad * 4 + r;
            if (row < S) {
                float v = o_acc[dt][r] / l_run[r];
                O[headoff + (size_t)row * C + dt * 16 + lane15] = (bf16)v;
            }
        }
    }
}

extern "C" void kernel_launch(void* const* d_in, const int* in_sizes, int n_in,
                              void* d_out, int out_size, void* d_ws, size_t ws_size,
                              hipStream_t stream) {
    float* out = (float*)d_out;
    const float* x_f32 = (const float*)d_in[0];
    const int M = 6000, Cc = 1024, F = 4096, Aa = 256;
    const size_t MC = (size_t)M * Cc;
    const size_t VT_ELEMS = (size_t)64 * 64 * 1536;   // 6,291,456
    bf16* ws = (bf16*)d_ws;

    bf16* h1 = ws;                         // [M,C]
    bf16* k  = ws + MC;                    // [M,C]
    bf16* Vt = ws + 2 * MC;                // [64][64][1536]
    bf16* g  = ws + 2 * MC + VT_ELEMS;     // [M,F]
    bf16* q  = (bf16*)d_out;               // d_out spare half as scratch (12.3 of 24.6 MB)
    bf16* wv = h1;                         // h1 dead after V gemm
    bf16* x1 = q;                          // q dead after attention
    bf16* h2 = k;                          // k dead after attention
    bf16* x2 = Vt;                         // Vt dead after attention
    bf16* aact = k;                        // k region free after MLP1

    // weight shadows
    bf16* conv[20];
    size_t off = 2 * MC + VT_ELEMS + (size_t)M * F;
    conv[0] = nullptr;
    for (int i = 1; i < 20; i++) {
        conv[i] = ws + off;
        off += ((size_t)in_sizes[i] + 63) & ~(size_t)63;
    }

    ConvArgs ca;
    int bacc = 0;
    for (int i = 0; i < 19; i++) {
        ca.src[i] = (const float*)d_in[i + 1];
        ca.dst[i] = conv[i + 1];
        ca.n[i] = in_sizes[i + 1];
        ca.bstart[i] = bacc;
        bacc += (in_sizes[i + 1] + 2047) / 2048;
    }
    ca.bstart[19] = bacc;

    dim3 blk(256);
    convert_many<<<bacc, blk, 0, stream>>>(ca);

    const bf16 *Wq = conv[1], *bq = conv[2], *Wk = conv[3], *Wv = conv[4],
               *bv = conv[5], *Wo = conv[6], *bo = conv[7], *lnw = conv[8], *lnb = conv[9],
               *W1 = conv[10], *b1 = conv[11], *W2 = conv[12], *b2 = conv[13],
               *ln2w = conv[14], *ln2b = conv[15], *Wds = conv[16], *bds = conv[17],
               *Wus = conv[18], *bus = conv[19];

    const float scale = 0.35355339059327373f;  // 64^-0.25
    dim3 gN(47, 8);    // N=1024
    dim3 gF(47, 32);   // N=4096
    dim3 gA(47, 2);    // N=256

    ln_kernel<float><<<M, blk, 0, stream>>>(x_f32, lnw, lnb, h1);
    gemm_kernel<0, 0, bf16, bf16><<<gN, blk, 0, stream>>>(h1, Wq, bq,      (const bf16*)nullptr, q,  M, Cc, Cc, scale);
    gemm_kernel<0, 0, bf16, bf16><<<gN, blk, 0, stream>>>(h1, Wk, nullptr, (const bf16*)nullptr, k,  M, Cc, Cc, scale);
    gemm_kernel<0, 1, bf16, bf16><<<gN, blk, 0, stream>>>(h1, Wv, bv,      (const bf16*)nullptr, Vt, M, Cc, Cc, 1.0f);
    dim3 ga(24, 64);
    flash_attn_kernel<<<ga, blk, 0, stream>>>(q, k, Vt, wv);
    gemm_kernel<0, 0, float, bf16><<<gN, blk, 0, stream>>>(wv, Wo, bo, x_f32, x1, M, Cc, Cc, 1.0f);
    ln_kernel<bf16><<<M, blk, 0, stream>>>(x1, ln2w, ln2b, h2);
    gemm_kernel<1, 0, bf16, bf16><<<gF, blk, 0, stream>>>(h2, W1, b1, (const bf16*)nullptr, g,  M, F,  Cc, 1.0f);
    gemm_kernel<0, 0, bf16, bf16><<<gN, blk, 0, stream>>>(g,  W2, b2, x1,      x2, M, Cc, F,  1.0f);
    gemm_kernel<1, 0, bf16, bf16><<<gA, blk, 0, stream>>>(x2, Wds, bds, (const bf16*)nullptr, aact, M, Aa, Cc, 1.0f);
    gemm_kernel<0, 0, bf16, float><<<gN, blk, 0, stream>>>(aact, Wus, bus, x2, out, M, Cc, Aa, 1.0f);
}